// Round 1
// baseline (1997.905 us; speedup 1.0000x reference)
//
#include <hip/hip_runtime.h>
#include <hip/hip_bf16.h>

#define B_ROWS 4096
#define D_INP 2048
#define DH 32768
#define TOPK 64
#define NCAND 96

typedef unsigned short ushort_t;
typedef unsigned int uint_t;
typedef __attribute__((ext_vector_type(8))) short bf16x8;
typedef __attribute__((ext_vector_type(4))) float f32x4;

__device__ __forceinline__ ushort_t f2bf(float f) {
  unsigned u = __float_as_uint(f);
  u += 0x7FFFu + ((u >> 16) & 1u);
  return (ushort_t)(u >> 16);
}

__device__ __forceinline__ void gload_lds16(const void* g, void* l) {
  __builtin_amdgcn_global_load_lds(
      (const __attribute__((address_space(1))) unsigned int*)g,
      (__attribute__((address_space(3))) unsigned int*)l, 16, 0, 0);
}

// ---------------- convert x - b_dec -> bf16 ----------------
__global__ __launch_bounds__(256) void k_convert_x(const float* __restrict__ x,
                                                   const float* __restrict__ b_dec,
                                                   ushort_t* __restrict__ xbf) {
  size_t i = ((size_t)blockIdx.x * 256 + threadIdx.x) * 8;
  float4 a0 = *(const float4*)(x + i);
  float4 a1 = *(const float4*)(x + i + 4);
  int c = (int)(i & (D_INP - 1));
  float4 d0 = *(const float4*)(b_dec + c);
  float4 d1 = *(const float4*)(b_dec + c + 4);
  union { ushort_t u[8]; uint4 v; } o;
  o.u[0] = f2bf(a0.x - d0.x); o.u[1] = f2bf(a0.y - d0.y);
  o.u[2] = f2bf(a0.z - d0.z); o.u[3] = f2bf(a0.w - d0.w);
  o.u[4] = f2bf(a1.x - d1.x); o.u[5] = f2bf(a1.y - d1.y);
  o.u[6] = f2bf(a1.z - d1.z); o.u[7] = f2bf(a1.w - d1.w);
  *(uint4*)(xbf + i) = o.v;
}

// ---------------- convert W_enc -> bf16 ----------------
__global__ __launch_bounds__(256) void k_convert_w(const float* __restrict__ w,
                                                   ushort_t* __restrict__ wbf) {
  size_t i = ((size_t)blockIdx.x * 256 + threadIdx.x) * 8;
  float4 a0 = *(const float4*)(w + i);
  float4 a1 = *(const float4*)(w + i + 4);
  union { ushort_t u[8]; uint4 v; } o;
  o.u[0] = f2bf(a0.x); o.u[1] = f2bf(a0.y); o.u[2] = f2bf(a0.z); o.u[3] = f2bf(a0.w);
  o.u[4] = f2bf(a1.x); o.u[5] = f2bf(a1.y); o.u[6] = f2bf(a1.z); o.u[7] = f2bf(a1.w);
  *(uint4*)(wbf + i) = o.v;
}

// ---------------- transpose W_dec [2048][32768] -> Wt [32768][2048] ----------------
__global__ __launch_bounds__(256) void k_transpose(const float* __restrict__ Wd,
                                                   float* __restrict__ Wt) {
  __shared__ float t[64][65];
  int tid = threadIdx.x;
  int tx = tid & 63, ty = tid >> 6;  // ty 0..3
  int bx = blockIdx.x;               // over DH/64 = 512
  int by = blockIdx.y;               // over D_INP/64 = 32
#pragma unroll
  for (int j = 0; j < 16; ++j) {
    int r = ty + j * 4;
    t[r][tx] = Wd[(size_t)(by * 64 + r) * DH + bx * 64 + tx];
  }
  __syncthreads();
#pragma unroll
  for (int j = 0; j < 16; ++j) {
    int r = ty + j * 4;
    Wt[(size_t)(bx * 64 + r) * D_INP + by * 64 + tx] = t[tx][r];
  }
}

// ---------------- coarse bf16 GEMM: C[4096][32768](bf16) = Xc @ W_enc^T ----------------
// m97-style 128x128 tile, BK=32, 4 waves, global_load_lds staging.
__global__ __launch_bounds__(256) void k_gemm_coarse(const ushort_t* __restrict__ A,
                                                     const ushort_t* __restrict__ W,
                                                     ushort_t* __restrict__ C) {
  __shared__ ushort_t As[128 * 32];
  __shared__ ushort_t Bs[128 * 32];
  int tid = threadIdx.x;
  int bid = blockIdx.x;
  // XCD swizzle (8192 blocks, 8 XCDs): contiguous 1024-block chunk per XCD,
  // bm fast-varying so 32 consecutive blocks share one W_enc panel (L2-resident).
  int swz = ((bid & 7) << 10) | (bid >> 3);
  int bm = swz & 31;   // 32 M-blocks
  int bn = swz >> 5;   // 256 N-blocks
  int lane = tid & 63;
  int wave = tid >> 6;
  int wm = (wave & 1) << 6;
  int wn = (wave >> 1) << 6;
  int arow = lane & 15;
  int koff = (lane >> 4) << 3;

  f32x4 acc[4][4] = {};

  const ushort_t* ga = A + (size_t)(bm * 128 + (tid >> 2)) * D_INP + (tid & 3) * 8;
  const ushort_t* gb = W + (size_t)(bn * 128 + (tid >> 2)) * D_INP + (tid & 3) * 8;
  ushort_t* la = As + tid * 8;
  ushort_t* lb = Bs + tid * 8;

  for (int kt = 0; kt < D_INP; kt += 32) {
    gload_lds16(ga + kt, la);
    gload_lds16(ga + 64 * D_INP + kt, la + 2048);
    gload_lds16(gb + kt, lb);
    gload_lds16(gb + 64 * D_INP + kt, lb + 2048);
    __syncthreads();
    bf16x8 av[4], bv[4];
#pragma unroll
    for (int f = 0; f < 4; ++f) {
      av[f] = *(const bf16x8*)(As + (wm + f * 16 + arow) * 32 + koff);
      bv[f] = *(const bf16x8*)(Bs + (wn + f * 16 + arow) * 32 + koff);
    }
#pragma unroll
    for (int i = 0; i < 4; ++i)
#pragma unroll
      for (int j = 0; j < 4; ++j)
        acc[i][j] = __builtin_amdgcn_mfma_f32_16x16x32_bf16(av[i], bv[j], acc[i][j], 0, 0, 0);
    __syncthreads();
  }

  int row0 = bm * 128 + wm + ((lane >> 4) << 2);
  int col0 = bn * 128 + wn + (lane & 15);
#pragma unroll
  for (int i = 0; i < 4; ++i)
#pragma unroll
    for (int r = 0; r < 4; ++r) {
      size_t rb = (size_t)(row0 + i * 16 + r) * DH + col0;
#pragma unroll
      for (int j = 0; j < 4; ++j)
        C[rb + j * 16] = f2bf(acc[i][j][r]);
    }
}

// ---------------- per-row top-96 radix select on 16-bit sortable keys ----------------
__device__ __forceinline__ uint_t bf2key(uint_t v) {
  return (v & 0x8000u) ? (~v & 0xFFFFu) : (v | 0x8000u);
}

__global__ __launch_bounds__(256) void k_topk(const ushort_t* __restrict__ C,
                                              uint_t* __restrict__ cand) {
  __shared__ uint_t hist[256];
  __shared__ uint_t sh_h, sh_cnt, sh_T;
  __shared__ uint_t ncand, ntie;
  __shared__ uint_t ties[256];
  int tid = threadIdx.x;
  int row = blockIdx.x;
  const uint4* rp = (const uint4*)(C + (size_t)row * DH);

  hist[tid] = 0;
  __syncthreads();
  // pass 1: high-byte histogram
  for (int j = 0; j < 16; ++j) {
    uint4 v = rp[tid + j * 256];
    uint_t w[4] = {v.x, v.y, v.z, v.w};
#pragma unroll
    for (int q = 0; q < 4; ++q) {
      uint_t k0 = bf2key(w[q] & 0xFFFFu);
      uint_t k1 = bf2key(w[q] >> 16);
      atomicAdd(&hist[k0 >> 8], 1u);
      atomicAdd(&hist[k1 >> 8], 1u);
    }
  }
  __syncthreads();
  if (tid == 0) {
    uint_t cum = 0; int b = 255;
    for (; b > 0; --b) { uint_t h = hist[b]; if (cum + h >= NCAND) break; cum += h; }
    sh_h = (uint_t)b; sh_cnt = cum;
  }
  __syncthreads();
  uint_t hstar = sh_h, cnt_hi = sh_cnt;
  hist[tid] = 0;
  __syncthreads();
  // pass 2: low-byte histogram among keys with high byte == hstar
  for (int j = 0; j < 16; ++j) {
    uint4 v = rp[tid + j * 256];
    uint_t w[4] = {v.x, v.y, v.z, v.w};
#pragma unroll
    for (int q = 0; q < 4; ++q) {
      uint_t k0 = bf2key(w[q] & 0xFFFFu);
      uint_t k1 = bf2key(w[q] >> 16);
      if ((k0 >> 8) == hstar) atomicAdd(&hist[k0 & 255u], 1u);
      if ((k1 >> 8) == hstar) atomicAdd(&hist[k1 & 255u], 1u);
    }
  }
  __syncthreads();
  if (tid == 0) {
    uint_t cum = cnt_hi; int b = 255;
    for (; b > 0; --b) { uint_t h = hist[b]; if (cum + h >= NCAND) break; cum += h; }
    sh_T = (hstar << 8) | (uint_t)b;
    ncand = 0; ntie = 0;
  }
  __syncthreads();
  uint_t T = sh_T;
  // pass 3: select strictly-greater; collect ties
  for (int j = 0; j < 16; ++j) {
    uint4 v = rp[tid + j * 256];
    uint_t w[4] = {v.x, v.y, v.z, v.w};
    int base = (tid + j * 256) * 8;
#pragma unroll
    for (int q = 0; q < 4; ++q) {
      uint_t k0 = bf2key(w[q] & 0xFFFFu);
      uint_t k1 = bf2key(w[q] >> 16);
      if (k0 > T) { uint_t p = atomicAdd(&ncand, 1u); cand[(size_t)row * NCAND + p] = base + 2 * q; }
      else if (k0 == T) { uint_t t = atomicAdd(&ntie, 1u); if (t < 256) ties[t] = base + 2 * q; }
      if (k1 > T) { uint_t p = atomicAdd(&ncand, 1u); cand[(size_t)row * NCAND + p] = base + 2 * q + 1; }
      else if (k1 == T) { uint_t t = atomicAdd(&ntie, 1u); if (t < 256) ties[t] = base + 2 * q + 1; }
    }
  }
  __syncthreads();
  if (tid == 0) {
    uint_t nc = ncand;
    for (uint_t j = 0; nc + j < NCAND; ++j) cand[(size_t)row * NCAND + nc + j] = ties[j];
  }
}

// ---------------- exact f64 recompute of candidates + rank -> top-64 ----------------
__global__ __launch_bounds__(256) void k_recompute(
    const float* __restrict__ x, const float* __restrict__ W_enc,
    const float* __restrict__ b_enc, const float* __restrict__ b_dec,
    const uint_t* __restrict__ cand, uint_t* __restrict__ tki,
    float* __restrict__ tkv, float* __restrict__ rl0) {
  __shared__ float xc[D_INP];
  __shared__ double vals[NCAND];
  __shared__ uint_t idxs[NCAND];
  __shared__ uint_t l0c;
  int tid = threadIdx.x, lane = tid & 63, wave = tid >> 6;
  int row = blockIdx.x;
#pragma unroll
  for (int j = 0; j < 2; ++j) {
    int c = tid * 4 + j * 1024;
    float4 xv = *(const float4*)(x + (size_t)row * D_INP + c);
    float4 dv = *(const float4*)(b_dec + c);
    *(float4*)(xc + c) = make_float4(xv.x - dv.x, xv.y - dv.y, xv.z - dv.z, xv.w - dv.w);
  }
  if (tid == 0) l0c = 0;
  __syncthreads();
  for (int ci = wave; ci < NCAND; ci += 4) {
    uint_t f = cand[(size_t)row * NCAND + ci];
    const float* wr = W_enc + (size_t)f * D_INP;
    double acc = 0.0;
#pragma unroll
    for (int j = 0; j < 8; ++j) {
      float4 wv = *(const float4*)(wr + lane * 4 + j * 256);
      float4 xv = *(const float4*)(xc + lane * 4 + j * 256);
      acc += (double)xv.x * wv.x + (double)xv.y * wv.y +
             (double)xv.z * wv.z + (double)xv.w * wv.w;
    }
#pragma unroll
    for (int off = 32; off; off >>= 1) acc += __shfl_xor(acc, off);
    if (lane == 0) { vals[ci] = acc + (double)b_enc[f]; idxs[ci] = f; }
  }
  __syncthreads();
  if (tid < NCAND) {
    double v = vals[tid]; uint_t f = idxs[tid];
    int rank = 0;
    for (int j = 0; j < NCAND; ++j) {
      double vj = vals[j];
      rank += (int)((vj > v) || (vj == v && idxs[j] < f));
    }
    if (rank < TOPK) {
      tki[(size_t)row * TOPK + rank] = f;
      float zv = v > 0.0 ? (float)v : 0.0f;
      tkv[(size_t)row * TOPK + rank] = zv;
      if (zv > 0.0f) atomicAdd(&l0c, 1u);
    }
  }
  __syncthreads();
  if (tid == 0) rl0[row] = (float)l0c;
}

// ---------------- sparse decode + per-row squared-error ----------------
__global__ __launch_bounds__(256) void k_decode(
    const float* __restrict__ x, const float* __restrict__ Wt,
    const float* __restrict__ b_dec, const uint_t* __restrict__ tki,
    const float* __restrict__ tkv, float* __restrict__ xhat,
    double* __restrict__ rsq) {
  __shared__ uint_t sidx[TOPK];
  __shared__ float sval[TOPK];
  __shared__ double wsum[4];
  int tid = threadIdx.x, lane = tid & 63, wave = tid >> 6;
  int row = blockIdx.x;
  if (tid < TOPK) {
    sidx[tid] = tki[(size_t)row * TOPK + tid];
    sval[tid] = tkv[(size_t)row * TOPK + tid];
  }
  __syncthreads();
  int c0 = tid * 8;
  float4 a0 = *(const float4*)(b_dec + c0);
  float4 a1 = *(const float4*)(b_dec + c0 + 4);
#pragma unroll 1
  for (int i = 0; i < TOPK; ++i) {
    float v = sval[i];
    const float* wr = Wt + (size_t)sidx[i] * D_INP + c0;
    float4 w0 = *(const float4*)wr;
    float4 w1 = *(const float4*)(wr + 4);
    a0.x += v * w0.x; a0.y += v * w0.y; a0.z += v * w0.z; a0.w += v * w0.w;
    a1.x += v * w1.x; a1.y += v * w1.y; a1.z += v * w1.z; a1.w += v * w1.w;
  }
  *(float4*)(xhat + (size_t)row * D_INP + c0) = a0;
  *(float4*)(xhat + (size_t)row * D_INP + c0 + 4) = a1;
  float4 x0 = *(const float4*)(x + (size_t)row * D_INP + c0);
  float4 x1 = *(const float4*)(x + (size_t)row * D_INP + c0 + 4);
  double s = 0.0;
  { float d;
    d = a0.x - x0.x; s += (double)d * d;
    d = a0.y - x0.y; s += (double)d * d;
    d = a0.z - x0.z; s += (double)d * d;
    d = a0.w - x0.w; s += (double)d * d;
    d = a1.x - x1.x; s += (double)d * d;
    d = a1.y - x1.y; s += (double)d * d;
    d = a1.z - x1.z; s += (double)d * d;
    d = a1.w - x1.w; s += (double)d * d; }
#pragma unroll
  for (int off = 32; off; off >>= 1) s += __shfl_xor(s, off);
  if (lane == 0) wsum[wave] = s;
  __syncthreads();
  if (tid == 0) rsq[row] = (wsum[0] + wsum[1]) + (wsum[2] + wsum[3]);
}

// ---------------- z write: zeros + 64 scattered values per row ----------------
__global__ __launch_bounds__(256) void k_zwrite(float* __restrict__ z,
                                                const uint_t* __restrict__ tki,
                                                const float* __restrict__ tkv) {
  int tid = threadIdx.x;
  int row = blockIdx.x;
  float4* zr = (float4*)(z + (size_t)row * DH);
  float4 zero = make_float4(0.f, 0.f, 0.f, 0.f);
#pragma unroll
  for (int j = 0; j < 32; ++j) zr[tid + j * 256] = zero;
  __syncthreads();
  if (tid < TOPK)
    z[(size_t)row * DH + tki[(size_t)row * TOPK + tid]] = tkv[(size_t)row * TOPK + tid];
}

// ---------------- finalize loss / l0 ----------------
__global__ __launch_bounds__(256) void k_finalize(const double* __restrict__ rsq,
                                                  const float* __restrict__ rl0,
                                                  float* __restrict__ o) {
  __shared__ double ss[4], sl[4];
  int tid = threadIdx.x, lane = tid & 63, wave = tid >> 6;
  double s = 0.0, l = 0.0;
  for (int i = tid; i < B_ROWS; i += 256) { s += rsq[i]; l += (double)rl0[i]; }
#pragma unroll
  for (int off = 32; off; off >>= 1) { s += __shfl_xor(s, off); l += __shfl_xor(l, off); }
  if (lane == 0) { ss[wave] = s; sl[wave] = l; }
  __syncthreads();
  if (tid == 0) {
    double st = (ss[0] + ss[1]) + (ss[2] + ss[3]);
    double lt = (sl[0] + sl[1]) + (sl[2] + sl[3]);
    o[0] = (float)(st / (double)((size_t)B_ROWS * D_INP));
    o[1] = (float)(lt / (double)B_ROWS);
  }
}

extern "C" void kernel_launch(void* const* d_in, const int* in_sizes, int n_in,
                              void* d_out, int out_size, void* d_ws, size_t ws_size,
                              hipStream_t stream) {
  const float* x = (const float*)d_in[0];
  const float* W_enc = (const float*)d_in[1];
  const float* b_enc = (const float*)d_in[2];
  const float* W_dec = (const float*)d_in[3];
  const float* b_dec = (const float*)d_in[4];
  // d_in[5] = k (always 64 for this problem)

  float* out = (float*)d_out;
  float* xhat = out;
  float* z = out + (size_t)B_ROWS * D_INP;
  // scratch aliased into the z output region (rewritten at the end):
  ushort_t* coarse = (ushort_t*)z;                         // 268 MB bf16 pre_acts
  float* Wt = z + (size_t)B_ROWS * DH / 2;                 // 268 MB W_dec^T
  float* lossp = out + (size_t)B_ROWS * D_INP + (size_t)B_ROWS * DH;

  const size_t OFF_XBF = 0;
  const size_t OFF_WBF = (size_t)B_ROWS * D_INP * 2;                 // 16 MB
  const size_t OFF_CAND = OFF_WBF + (size_t)DH * D_INP * 2;          // +134 MB
  const size_t OFF_TKI = OFF_CAND + (size_t)B_ROWS * NCAND * 4;
  const size_t OFF_TKV = OFF_TKI + (size_t)B_ROWS * TOPK * 4;
  const size_t OFF_RSQ = OFF_TKV + (size_t)B_ROWS * TOPK * 4;
  const size_t OFF_RL0 = OFF_RSQ + (size_t)B_ROWS * 8;
  const size_t WS_NEED = OFF_RL0 + (size_t)B_ROWS * 4;
  if (ws_size < WS_NEED) return;  // workspace too small: fail cleanly, no OOB

  char* ws = (char*)d_ws;
  ushort_t* xbf = (ushort_t*)(ws + OFF_XBF);
  ushort_t* wbf = (ushort_t*)(ws + OFF_WBF);
  uint_t* cand = (uint_t*)(ws + OFF_CAND);
  uint_t* tki = (uint_t*)(ws + OFF_TKI);
  float* tkv = (float*)(ws + OFF_TKV);
  double* rsq = (double*)(ws + OFF_RSQ);
  float* rl0 = (float*)(ws + OFF_RL0);

  k_convert_x<<<dim3(4096), dim3(256), 0, stream>>>(x, b_dec, xbf);
  k_convert_w<<<dim3(32768), dim3(256), 0, stream>>>(W_enc, wbf);
  k_transpose<<<dim3(512, 32), dim3(256), 0, stream>>>(W_dec, Wt);
  k_gemm_coarse<<<dim3(8192), dim3(256), 0, stream>>>(xbf, wbf, coarse);
  k_topk<<<dim3(4096), dim3(256), 0, stream>>>(coarse, cand);
  k_recompute<<<dim3(4096), dim3(256), 0, stream>>>(x, W_enc, b_enc, b_dec, cand, tki, tkv, rl0);
  k_decode<<<dim3(4096), dim3(256), 0, stream>>>(x, Wt, b_dec, tki, tkv, xhat, rsq);
  k_zwrite<<<dim3(4096), dim3(256), 0, stream>>>(z, tki, tkv);
  k_finalize<<<dim3(1), dim3(256), 0, stream>>>(rsq, rl0, lossp);
}